// Round 1
// baseline (93090.320 us; speedup 1.0000x reference)
//
#include <hip/hip_runtime.h>

// Problem constants
#define Hh   512
#define Vv   128
#define LL   8192
#define G3   1536      // 3*H
#define NB   128       // persistent blocks in seq kernel
#define EPB  4         // hidden elements owned per block per layer (512/128)
#define ROWS 36        // 3 matrices * 3 gates * EPB rows per block
#define WST  520       // padded LDS row stride (f32 words): 520%32=8 -> 2-way bank alias (free)

// workspace layout (bytes)
#define OFF_GX   0ull                      // 8192*1536*4 = 50,331,648
#define OFF_YS   50331648ull               // 8192*512*4  = 16,777,216
#define OFF_H0R  67108864ull               // 2*512*4     = 4096
#define OFF_H1R  (OFF_H0R + 4096ull)       // 4096
#define OFF_FLAG (OFF_H0R + 8192ull)       // 128*4 -> pad 512
#define OFF_WT   (OFF_H0R + 12288ull)      // 512*128*4 = 262,144

#define LDS_WORDS (ROWS*WST + 40 + 40 + 512 + 512)
#define LDS_BYTES (LDS_WORDS * 4)

__device__ __forceinline__ float sigm(float x)  { return 1.f / (1.f + __expf(-x)); }
__device__ __forceinline__ float tanha(float x) { return 2.f / (1.f + __expf(-2.f * x)) - 1.f; }

// ---------------------------------------------------------------------------
// gx = X @ Wih^T + bih  (per-row gate pre-activation for layer 0)
// grid (L/16, 1536/256), block 256. shift_relu: decoder input = relu(trg[max(t-1,0)])
// ---------------------------------------------------------------------------
__global__ __launch_bounds__(256) void gemm_gx(
    const float* __restrict__ X, const float* __restrict__ Wih,
    const float* __restrict__ bih, float* __restrict__ gxo, int shift_relu)
{
    __shared__ float xs[16][128];
    const int tid = threadIdx.x;
    const int m0  = blockIdx.x * 16;
    const int c   = blockIdx.y * 256 + tid;   // 0..1535 (row of Wih)

    for (int i = tid; i < 16 * 128; i += 256) {
        const int r = i >> 7, k = i & 127;
        int srow = m0 + r;
        if (shift_relu) srow = (srow == 0) ? 0 : (srow - 1);
        float v = X[(size_t)srow * Vv + k];
        if (shift_relu) v = fmaxf(v, 0.f);
        xs[r][k] = v;
    }
    __syncthreads();

    const float4* wp = (const float4*)(Wih + (size_t)c * Vv);
    float4 wr[32];
#pragma unroll
    for (int q = 0; q < 32; ++q) wr[q] = wp[q];
    const float bb = bih[c];

    for (int m = 0; m < 16; ++m) {
        const float4* xp = (const float4*)xs[m];
        float acc = bb;
#pragma unroll
        for (int q = 0; q < 32; ++q) {
            const float4 x4 = xp[q];
            acc = fmaf(wr[q].x, x4.x, acc); acc = fmaf(wr[q].y, x4.y, acc);
            acc = fmaf(wr[q].z, x4.z, acc); acc = fmaf(wr[q].w, x4.w, acc);
        }
        gxo[(size_t)(m0 + m) * G3 + c] = acc;
    }
}

// ---------------------------------------------------------------------------
// Persistent 2-layer GRU scan. 128 blocks, 256 threads. Layer 1 lags layer 0
// by one tick -> single grid barrier per tick (distributed flags, agent scope).
// Block owns elements [bid*4, bid*4+4) of both layers; its 36 weight rows
// (Whh0 / Wih1 / Whh1 x 3 gates x 4 elems) live in LDS for the whole kernel.
// h state in 2-slot global rings, published via write-through atomic stores.
// ---------------------------------------------------------------------------
__global__ __launch_bounds__(256) void seq2(
    const float* __restrict__ gx,
    const float* __restrict__ Whh0, const float* __restrict__ Wih1,
    const float* __restrict__ Whh1,
    const float* __restrict__ bhh0, const float* __restrict__ bih1,
    const float* __restrict__ bhh1,
    float* __restrict__ h0r, float* __restrict__ h1r,
    float* __restrict__ ys, unsigned* __restrict__ flags)
{
    const int bid = blockIdx.x, tid = threadIdx.x;
    extern __shared__ float lds[];
    float* Wl  = lds;                  // [ROWS][WST]
    float* ghv = lds + ROWS * WST;     // 36 dot results (pad 40)
    float* bl  = ghv + 40;             // 36 biases (pad 40)
    float* hs0 = bl + 40;              // staged h0(tau-1), 512
    float* hs1 = hs0 + 512;            // staged h1(tau-2), 512

    // one-time stage: weight rows + biases for this block's elements
    for (int r = 0; r < ROWS; ++r) {
        const int m = r / 12, g = (r % 12) / 4, e = r % 4;
        const float* srcW = (m == 0 ? Whh0 : (m == 1 ? Wih1 : Whh1))
                            + (size_t)(g * Hh + bid * EPB + e) * Hh;
        for (int k = tid; k < Hh; k += 256) Wl[r * WST + k] = srcW[k];
    }
    if (tid < ROWS) {
        const int m = tid / 12, g = (tid % 12) / 4, e = tid % 4;
        const float* bsrc = (m == 0 ? bhh0 : (m == 1 ? bih1 : bhh1));
        bl[tid] = bsrc[g * Hh + bid * EPB + e];
    }
    __syncthreads();

    const int rw = tid >> 3;           // row within pass (0..31)
    const int kb = (tid & 7) * 64;     // 64-float K chunk per lane

    for (int tau = 0; tau <= LL; ++tau) {
        // prefetch gx row (independent of barrier -> latency hides under spin)
        float xr = 0.f, xz = 0.f, xn = 0.f;
        if (tid < EPB && tau < LL) {
            const size_t gb = (size_t)tau * G3 + bid * EPB + tid;
            xr = gx[gb]; xz = gx[gb + Hh]; xn = gx[gb + 2 * Hh];
        }

        // grid barrier: all blocks finished tick tau-1
        if (tid < 64) {
            for (;;) {
                const unsigned a = __hip_atomic_load(&flags[tid],      __ATOMIC_RELAXED, __HIP_MEMORY_SCOPE_AGENT);
                const unsigned b = __hip_atomic_load(&flags[tid + 64], __ATOMIC_RELAXED, __HIP_MEMORY_SCOPE_AGENT);
                if ((int)a >= tau && (int)b >= tau) break;
                __builtin_amdgcn_s_sleep(1);
            }
        }
        __syncthreads();

        // stage h0(tau-1) and h1(tau-2) into LDS (cache-bypassing atomic loads)
        {
            const unsigned long long u0 = __hip_atomic_load(
                (const unsigned long long*)(h0r + ((tau - 1) & 1) * Hh) + tid,
                __ATOMIC_RELAXED, __HIP_MEMORY_SCOPE_AGENT);
            const unsigned long long u1 = __hip_atomic_load(
                (const unsigned long long*)(h1r + ((tau - 2) & 1) * Hh) + tid,
                __ATOMIC_RELAXED, __HIP_MEMORY_SCOPE_AGENT);
            *(float2*)(hs0 + 2 * tid) = __builtin_bit_cast(float2, u0);
            *(float2*)(hs1 + 2 * tid) = __builtin_bit_cast(float2, u1);
        }
        __syncthreads();

        // 36 dot products: rows 0..11 Whh0@h0, 12..23 Wih1@h0 (=c0), 24..35 Whh1@h1
        {
            const int r = rw;
            const float* hv = (r < 24) ? hs0 : hs1;
            const float4* wp = (const float4*)(Wl + r * WST + kb);
            const float4* hp = (const float4*)(hv + kb);
            float acc = 0.f;
#pragma unroll
            for (int q = 0; q < 16; ++q) {
                const float4 w = wp[q], h = hp[q];
                acc = fmaf(w.x, h.x, acc); acc = fmaf(w.y, h.y, acc);
                acc = fmaf(w.z, h.z, acc); acc = fmaf(w.w, h.w, acc);
            }
            acc += __shfl_xor(acc, 1); acc += __shfl_xor(acc, 2); acc += __shfl_xor(acc, 4);
            if ((tid & 7) == 0) ghv[r] = acc;
        }
        if (tid < 32) {
            const int r = 32 + rw;     // rows 32..35 (Whh1, n-gate tail)
            const float4* wp = (const float4*)(Wl + r * WST + kb);
            const float4* hp = (const float4*)(hs1 + kb);
            float acc = 0.f;
#pragma unroll
            for (int q = 0; q < 16; ++q) {
                const float4 w = wp[q], h = hp[q];
                acc = fmaf(w.x, h.x, acc); acc = fmaf(w.y, h.y, acc);
                acc = fmaf(w.z, h.z, acc); acc = fmaf(w.w, h.w, acc);
            }
            acc += __shfl_xor(acc, 1); acc += __shfl_xor(acc, 2); acc += __shfl_xor(acc, 4);
            if ((tid & 7) == 0) ghv[r] = acc;
        }
        __syncthreads();

        // gate math: layer0 (step tau) on wave 0, layer1 (step tau-1) on wave 1
        if (tid < EPB && tau < LL) {
            const int e = tid, idx = bid * EPB + e;
            const float hr = ghv[e]     + bl[e];
            const float hz = ghv[4 + e] + bl[4 + e];
            const float hn = ghv[8 + e] + bl[8 + e];
            const float rg = sigm(xr + hr);
            const float zg = sigm(xz + hz);
            const float ng = tanha(xn + rg * hn);
            const float hnew = (1.f - zg) * ng + zg * hs0[idx];
            __hip_atomic_store(h0r + (tau & 1) * Hh + idx, hnew,
                               __ATOMIC_RELAXED, __HIP_MEMORY_SCOPE_AGENT);
        } else if (tid >= 64 && tid < 64 + EPB && tau >= 1) {
            const int e = tid - 64, idx = bid * EPB + e, sg = tau - 1;
            const float xr1 = ghv[12 + e] + bl[12 + e];
            const float xz1 = ghv[16 + e] + bl[16 + e];
            const float xn1 = ghv[20 + e] + bl[20 + e];
            const float hr1 = ghv[24 + e] + bl[24 + e];
            const float hz1 = ghv[28 + e] + bl[28 + e];
            const float hn1 = ghv[32 + e] + bl[32 + e];
            const float rg = sigm(xr1 + hr1);
            const float zg = sigm(xz1 + hz1);
            const float ng = tanha(xn1 + rg * hn1);
            const float hnew = (1.f - zg) * ng + zg * hs1[idx];
            __hip_atomic_store(h1r + (sg & 1) * Hh + idx, hnew,
                               __ATOMIC_RELAXED, __HIP_MEMORY_SCOPE_AGENT);
            if (ys) ys[(size_t)sg * Hh + idx] = hnew;
        }

        __threadfence_block();   // drain this thread's stores (write-through, acked at coherent point)
        __syncthreads();
        if (tid == 0)
            __hip_atomic_store(&flags[bid], (unsigned)(tau + 1),
                               __ATOMIC_RELAXED, __HIP_MEMORY_SCOPE_AGENT);
    }
}

// ---------------------------------------------------------------------------
// WoutT[k][c] = Wout[c][k]   (128x512 -> 512x128) for coalesced out_proj reads
// ---------------------------------------------------------------------------
__global__ __launch_bounds__(256) void transposeW(const float* __restrict__ W,
                                                  float* __restrict__ WT)
{
    const int i = blockIdx.x * 256 + threadIdx.x;  // 0..65535
    const int r = i >> 9, k = i & 511;
    WT[k * 128 + r] = W[i];
}

// ---------------------------------------------------------------------------
// out = sigmoid(ys @ Wout^T + bout).  grid L/16, block 128.
// ---------------------------------------------------------------------------
__global__ __launch_bounds__(128) void out_proj(
    const float* __restrict__ ys, const float* __restrict__ WT,
    const float* __restrict__ bout, float* __restrict__ out)
{
    __shared__ float yss[16][512];
    const int tid = threadIdx.x;
    const int m0  = blockIdx.x * 16;

    for (int i = tid; i < 16 * 512; i += 128)
        yss[i >> 9][i & 511] = ys[(size_t)(m0 + (i >> 9)) * 512 + (i & 511)];
    __syncthreads();

    const int c = tid;  // 0..127
    float acc[16];
    const float b = bout[c];
#pragma unroll
    for (int m = 0; m < 16; ++m) acc[m] = b;

    for (int k4 = 0; k4 < 128; ++k4) {
        const float w0 = WT[(4 * k4 + 0) * 128 + c];
        const float w1 = WT[(4 * k4 + 1) * 128 + c];
        const float w2 = WT[(4 * k4 + 2) * 128 + c];
        const float w3 = WT[(4 * k4 + 3) * 128 + c];
#pragma unroll
        for (int m = 0; m < 16; ++m) {
            const float4 yv = *(const float4*)&yss[m][4 * k4];
            acc[m] = fmaf(w0, yv.x, fmaf(w1, yv.y, fmaf(w2, yv.z, fmaf(w3, yv.w, acc[m]))));
        }
    }
#pragma unroll
    for (int m = 0; m < 16; ++m)
        out[(size_t)(m0 + m) * 128 + c] = 1.f / (1.f + __expf(-acc[m]));
}

// ---------------------------------------------------------------------------
extern "C" void kernel_launch(void* const* d_in, const int* in_sizes, int n_in,
                              void* d_out, int out_size, void* d_ws, size_t ws_size,
                              hipStream_t stream)
{
    const float* src      = (const float*)d_in[0];
    const float* trg      = (const float*)d_in[1];
    const float* eWih0    = (const float*)d_in[2];
    const float* eWhh0    = (const float*)d_in[3];
    const float* ebih0    = (const float*)d_in[4];
    const float* ebhh0    = (const float*)d_in[5];
    const float* eWih1    = (const float*)d_in[6];
    const float* eWhh1    = (const float*)d_in[7];
    const float* ebih1    = (const float*)d_in[8];
    const float* ebhh1    = (const float*)d_in[9];
    const float* dWih0    = (const float*)d_in[10];
    const float* dWhh0    = (const float*)d_in[11];
    const float* dbih0    = (const float*)d_in[12];
    const float* dbhh0    = (const float*)d_in[13];
    const float* dWih1    = (const float*)d_in[14];
    const float* dWhh1    = (const float*)d_in[15];
    const float* dbih1    = (const float*)d_in[16];
    const float* dbhh1    = (const float*)d_in[17];
    const float* Wout     = (const float*)d_in[18];
    const float* bout     = (const float*)d_in[19];

    char* ws = (char*)d_ws;
    float*    gx    = (float*)(ws + OFF_GX);
    float*    ys    = (float*)(ws + OFF_YS);
    float*    h0r   = (float*)(ws + OFF_H0R);
    float*    h1r   = (float*)(ws + OFF_H1R);
    unsigned* flags = (unsigned*)(ws + OFF_FLAG);
    float*    WT    = (float*)(ws + OFF_WT);

    // opt-in to >64KB dynamic LDS for the persistent kernel (idempotent, capture-safe)
    hipFuncSetAttribute(reinterpret_cast<const void*>(seq2),
                        hipFuncAttributeMaxDynamicSharedMemorySize, LDS_BYTES);

    // zero h rings + flags (encoder initial state = 0)
    hipMemsetAsync(ws + OFF_H0R, 0, 8704, stream);

    hipLaunchKernelGGL(transposeW, dim3(256), dim3(256), 0, stream, Wout, WT);

    // ---- encoder ----
    hipLaunchKernelGGL(gemm_gx, dim3(LL / 16, 6), dim3(256), 0, stream,
                       src, eWih0, ebih0, gx, 0);
    hipLaunchKernelGGL(seq2, dim3(NB), dim3(256), LDS_BYTES, stream,
                       gx, eWhh0, eWih1, eWhh1, ebhh0, ebih1, ebhh1,
                       h0r, h1r, (float*)nullptr, flags);

    // ---- decoder (rings carry encoder final states; flags must restart at 0) ----
    hipMemsetAsync(ws + OFF_FLAG, 0, 512, stream);
    hipLaunchKernelGGL(gemm_gx, dim3(LL / 16, 6), dim3(256), 0, stream,
                       trg, dWih0, dbih0, gx, 1);
    hipLaunchKernelGGL(seq2, dim3(NB), dim3(256), LDS_BYTES, stream,
                       gx, dWhh0, dWih1, dWhh1, dbhh0, dbih1, dbhh1,
                       h0r, h1r, ys, flags);

    // ---- output projection ----
    hipLaunchKernelGGL(out_proj, dim3(LL / 16), dim3(128), 0, stream,
                       ys, WT, bout, (float*)d_out);

    (void)in_sizes; (void)n_in; (void)out_size; (void)ws_size;
}

// Round 2
// 53203.461 us; speedup vs baseline: 1.7497x; 1.7497x over previous
//
#include <hip/hip_runtime.h>

// Problem constants
#define Hh   512
#define Vv   128
#define LL   8192
#define G3   1536      // 3*H
#define NB   128       // persistent blocks in seq kernel
#define EPB  4         // hidden elements owned per block per layer (512/128)
#define ROWS 36        // 3 matrices * 3 gates * EPB rows per block
#define WST  520       // padded LDS row stride (f32 words)
#define NPAIR 1024     // NB * 8 pairs per record slot

// workspace layout (bytes)
#define OFF_GX   0ull                       // 8192*1536*4 = 50,331,648
#define OFF_YS   50331648ull                // 8192*512*4  = 16,777,216
#define OFF_RECE 67108864ull                // 2*1024*8    = 16,384
#define OFF_RECD (OFF_RECE + 16384ull)      // 16,384
#define OFF_WT   (OFF_RECD + 16384ull)      // 512*128*4   = 262,144

#define LDS_WORDS (ROWS*WST + 40 + 40 + 512 + 512)
#define LDS_BYTES (LDS_WORDS * 4)

__device__ __forceinline__ float sigm(float x)  { return 1.f / (1.f + __expf(-x)); }
__device__ __forceinline__ float tanha(float x) { return 2.f / (1.f + __expf(-2.f * x)) - 1.f; }

__device__ __forceinline__ unsigned long long packpair(float v, int t) {
    return ((unsigned long long)(unsigned)t << 32) | (unsigned long long)__float_as_uint(v);
}
__device__ __forceinline__ int   pair_tag(unsigned long long p) { return (int)(p >> 32); }
__device__ __forceinline__ float pair_val(unsigned long long p) { return __uint_as_float((unsigned)p); }

// ---------------------------------------------------------------------------
// gx = X @ Wih^T + bih  (layer-0 input pre-activations, fully parallel)
// ---------------------------------------------------------------------------
__global__ __launch_bounds__(256) void gemm_gx(
    const float* __restrict__ X, const float* __restrict__ Wih,
    const float* __restrict__ bih, float* __restrict__ gxo, int shift_relu)
{
    __shared__ float xs[16][128];
    const int tid = threadIdx.x;
    const int m0  = blockIdx.x * 16;
    const int c   = blockIdx.y * 256 + tid;   // 0..1535 (row of Wih)

    for (int i = tid; i < 16 * 128; i += 256) {
        const int r = i >> 7, k = i & 127;
        int srow = m0 + r;
        if (shift_relu) srow = (srow == 0) ? 0 : (srow - 1);
        float v = X[(size_t)srow * Vv + k];
        if (shift_relu) v = fmaxf(v, 0.f);
        xs[r][k] = v;
    }
    __syncthreads();

    const float4* wp = (const float4*)(Wih + (size_t)c * Vv);
    float4 wr[32];
#pragma unroll
    for (int q = 0; q < 32; ++q) wr[q] = wp[q];
    const float bb = bih[c];

    for (int m = 0; m < 16; ++m) {
        const float4* xp = (const float4*)xs[m];
        float acc = bb;
#pragma unroll
        for (int q = 0; q < 32; ++q) {
            const float4 x4 = xp[q];
            acc = fmaf(wr[q].x, x4.x, acc); acc = fmaf(wr[q].y, x4.y, acc);
            acc = fmaf(wr[q].z, x4.z, acc); acc = fmaf(wr[q].w, x4.w, acc);
        }
        gxo[(size_t)(m0 + m) * G3 + c] = acc;
    }
}

// ---------------------------------------------------------------------------
// Persistent 2-layer GRU scan, layer 1 one tick behind layer 0.
// Synchronization: self-validating (value, tag) 8-byte pairs in a 2-slot ring.
// Record tau = { h0(tau)[512], h1(tau-1)[512] } as NB*8 pairs, tag = tau.
// A block publishes record tau at end of iteration tau; iteration tau consumes
// record tau-1. 2 slots suffice: publishing tau+1 (same slot as tau-1) requires
// all blocks' tags >= tau, i.e. all have consumed record tau-1. No fences.
// ---------------------------------------------------------------------------
__global__ __launch_bounds__(256) void seq2(
    const float* __restrict__ gx,
    const float* __restrict__ Whh0, const float* __restrict__ Wih1,
    const float* __restrict__ Whh1,
    const float* __restrict__ bhh0, const float* __restrict__ bih1,
    const float* __restrict__ bhh1,
    unsigned long long* __restrict__ rec,
    float* __restrict__ ys)
{
    const int bid = blockIdx.x, tid = threadIdx.x;
    extern __shared__ float lds[];
    float* Wl  = lds;                  // [ROWS][WST]
    float* ghv = lds + ROWS * WST;     // 36 dot results (pad 40)
    float* bl  = ghv + 40;             // 36 biases (pad 40)
    float* hs0 = bl + 40;              // h0(tau-1), 512
    float* hs1 = hs0 + 512;            // h1(tau-2), 512

    // one-time stage: weight rows + biases for this block's elements
    for (int r = 0; r < ROWS; ++r) {
        const int m = r / 12, g = (r % 12) / 4, e = r % 4;
        const float* srcW = (m == 0 ? Whh0 : (m == 1 ? Wih1 : Whh1))
                            + (size_t)(g * Hh + bid * EPB + e) * Hh;
        for (int k = tid; k < Hh; k += 256) Wl[r * WST + k] = srcW[k];
    }
    if (tid < ROWS) {
        const int m = tid / 12, g = (tid % 12) / 4, e = tid % 4;
        const float* bsrc = (m == 0 ? bhh0 : (m == 1 ? bih1 : bhh1));
        bl[tid] = bsrc[g * Hh + bid * EPB + e];
    }
    __syncthreads();

    const int g  = tid & 7;            // K-chunk lane within 8-lane group
    const int rw = tid >> 3;           // row handled by this group (0..31)

    for (int tau = 0; tau <= LL; ++tau) {
        // prefetch gx row (independent of the poll; latency hides under it)
        float xr = 0.f, xz = 0.f, xn = 0.f;
        if (tid < EPB && tau < LL) {
            const size_t gb = (size_t)tau * G3 + bid * EPB + tid;
            xr = gx[gb]; xz = gx[gb + Hh]; xn = gx[gb + 2 * Hh];
        }

        // poll record tau-1: 4 pairs per thread, each pair self-validating
        const int need = tau - 1;
        const unsigned long long* rp = rec + (size_t)((tau - 1) & 1) * NPAIR + 4 * tid;
        unsigned long long p0, p1, p2, p3;
        for (;;) {
            p0 = __hip_atomic_load(rp + 0, __ATOMIC_RELAXED, __HIP_MEMORY_SCOPE_AGENT);
            p1 = __hip_atomic_load(rp + 1, __ATOMIC_RELAXED, __HIP_MEMORY_SCOPE_AGENT);
            p2 = __hip_atomic_load(rp + 2, __ATOMIC_RELAXED, __HIP_MEMORY_SCOPE_AGENT);
            p3 = __hip_atomic_load(rp + 3, __ATOMIC_RELAXED, __HIP_MEMORY_SCOPE_AGENT);
            const int ok = (pair_tag(p0) >= need) & (pair_tag(p1) >= need) &
                           (pair_tag(p2) >= need) & (pair_tag(p3) >= need);
            if (__syncthreads_and(ok)) break;
        }

        // stage polled h values into LDS: even tid -> hs0, odd tid -> hs1
        {
            float4 hv = make_float4(pair_val(p0), pair_val(p1), pair_val(p2), pair_val(p3));
            float* dst = (tid & 1) ? (hs1 + 2 * (tid - 1)) : (hs0 + 2 * tid);
            *(float4*)dst = hv;
        }
        __syncthreads();

        // 36 dots: rows 0..11 Whh0@h0, 12..23 Wih1@h0, 24..35 Whh1@h1
        // interleaved chunks (float4 index g + 8q): 8 words/bank/inst for W
        // (conflict-free), h reads broadcast across the 8 rows of a wave.
        {
            const float4* wp = (const float4*)(Wl + rw * WST);
            const float4* hp = (const float4*)((rw < 24) ? hs0 : hs1);
            float acc = 0.f;
#pragma unroll
            for (int q = 0; q < 16; ++q) {
                const float4 w = wp[g + 8 * q];
                const float4 h = hp[g + 8 * q];
                acc = fmaf(w.x, h.x, acc); acc = fmaf(w.y, h.y, acc);
                acc = fmaf(w.z, h.z, acc); acc = fmaf(w.w, h.w, acc);
            }
            acc += __shfl_xor(acc, 1); acc += __shfl_xor(acc, 2); acc += __shfl_xor(acc, 4);
            if (g == 0) ghv[rw] = acc;
        }
        if (tid < 32) {
            const int r = 32 + rw;     // rows 32..35 (Whh1 n-gate tail)
            const float4* wp = (const float4*)(Wl + r * WST);
            const float4* hp = (const float4*)hs1;
            float acc = 0.f;
#pragma unroll
            for (int q = 0; q < 16; ++q) {
                const float4 w = wp[g + 8 * q];
                const float4 h = hp[g + 8 * q];
                acc = fmaf(w.x, h.x, acc); acc = fmaf(w.y, h.y, acc);
                acc = fmaf(w.z, h.z, acc); acc = fmaf(w.w, h.w, acc);
            }
            acc += __shfl_xor(acc, 1); acc += __shfl_xor(acc, 2); acc += __shfl_xor(acc, 4);
            if (g == 0) ghv[r] = acc;
        }
        __syncthreads();

        // gate math + publish (fire-and-forget, pair carries the tag)
        unsigned long long* recw = rec + (size_t)(tau & 1) * NPAIR + bid * 8;
        if (tid < EPB && tau < LL) {
            const int e = tid, idx = bid * EPB + e;
            const float hr = ghv[e]     + bl[e];
            const float hz = ghv[4 + e] + bl[4 + e];
            const float hn = ghv[8 + e] + bl[8 + e];
            const float rg = sigm(xr + hr);
            const float zg = sigm(xz + hz);
            const float ng = tanha(xn + rg * hn);
            const float hnew = (1.f - zg) * ng + zg * hs0[idx];
            __hip_atomic_store(recw + e, packpair(hnew, tau),
                               __ATOMIC_RELAXED, __HIP_MEMORY_SCOPE_AGENT);
        } else if (tid >= 64 && tid < 64 + EPB) {
            const int e = tid - 64, idx = bid * EPB + e, sg = tau - 1;
            float hnew;
            if (tau >= 1) {
                const float xr1 = ghv[12 + e] + bl[12 + e];
                const float xz1 = ghv[16 + e] + bl[16 + e];
                const float xn1 = ghv[20 + e] + bl[20 + e];
                const float hr1 = ghv[24 + e] + bl[24 + e];
                const float hz1 = ghv[28 + e] + bl[28 + e];
                const float hn1 = ghv[32 + e] + bl[32 + e];
                const float rg = sigm(xr1 + hr1);
                const float zg = sigm(xz1 + hz1);
                const float ng = tanha(xn1 + rg * hn1);
                hnew = (1.f - zg) * ng + zg * hs1[idx];
                if (ys) ys[(size_t)sg * Hh + idx] = hnew;
            } else {
                hnew = hs1[idx];       // pass initial h1 through as "h1(-1)"
            }
            __hip_atomic_store(recw + 4 + e, packpair(hnew, tau),
                               __ATOMIC_RELAXED, __HIP_MEMORY_SCOPE_AGENT);
        }
        // next iteration's poll barrier separates these LDS reads from restaging
    }
}

// ---------------------------------------------------------------------------
// WoutT + encoder record init (h=0, slot1 tag=-1 / slot0 tag=-2)
// ---------------------------------------------------------------------------
__global__ __launch_bounds__(256) void transposeW(const float* __restrict__ W,
                                                  float* __restrict__ WT,
                                                  unsigned long long* __restrict__ encr)
{
    const int i = blockIdx.x * 256 + threadIdx.x;  // 0..65535
    WT[(i & 511) * 128 + (i >> 9)] = W[i];
    if (i < NPAIR) {
        __hip_atomic_store(encr + NPAIR + i, packpair(0.f, -1),
                           __ATOMIC_RELAXED, __HIP_MEMORY_SCOPE_AGENT);
        __hip_atomic_store(encr + i, packpair(0.f, -2),
                           __ATOMIC_RELAXED, __HIP_MEMORY_SCOPE_AGENT);
    }
}

// ---------------------------------------------------------------------------
// encoder -> decoder state handoff: dec init record = {enc h0(L-1), enc h1(L-1)}
// enc h0(L-1) lives in slot (L-1)&1 = 1 (e<4), enc h1(L-1) in slot L&1 = 0 (e>=4)
// ---------------------------------------------------------------------------
__global__ __launch_bounds__(256) void handoff(const unsigned long long* __restrict__ encr,
                                               unsigned long long* __restrict__ decr)
{
    const int p = blockIdx.x * 256 + threadIdx.x;  // 0..1023
    const int e = p & 7;
    const unsigned long long src = __hip_atomic_load(
        encr + (e < 4 ? NPAIR : 0) + p, __ATOMIC_RELAXED, __HIP_MEMORY_SCOPE_AGENT);
    __hip_atomic_store(decr + NPAIR + p, packpair(pair_val(src), -1),
                       __ATOMIC_RELAXED, __HIP_MEMORY_SCOPE_AGENT);
    __hip_atomic_store(decr + p, packpair(0.f, -2),
                       __ATOMIC_RELAXED, __HIP_MEMORY_SCOPE_AGENT);
}

// ---------------------------------------------------------------------------
// out = sigmoid(ys @ Wout^T + bout)
// ---------------------------------------------------------------------------
__global__ __launch_bounds__(128) void out_proj(
    const float* __restrict__ ys, const float* __restrict__ WT,
    const float* __restrict__ bout, float* __restrict__ out)
{
    __shared__ float yss[16][512];
    const int tid = threadIdx.x;
    const int m0  = blockIdx.x * 16;

    for (int i = tid; i < 16 * 512; i += 128)
        yss[i >> 9][i & 511] = ys[(size_t)(m0 + (i >> 9)) * 512 + (i & 511)];
    __syncthreads();

    const int c = tid;  // 0..127
    float acc[16];
    const float b = bout[c];
#pragma unroll
    for (int m = 0; m < 16; ++m) acc[m] = b;

    for (int k4 = 0; k4 < 128; ++k4) {
        const float w0 = WT[(4 * k4 + 0) * 128 + c];
        const float w1 = WT[(4 * k4 + 1) * 128 + c];
        const float w2 = WT[(4 * k4 + 2) * 128 + c];
        const float w3 = WT[(4 * k4 + 3) * 128 + c];
#pragma unroll
        for (int m = 0; m < 16; ++m) {
            const float4 yv = *(const float4*)&yss[m][4 * k4];
            acc[m] = fmaf(w0, yv.x, fmaf(w1, yv.y, fmaf(w2, yv.z, fmaf(w3, yv.w, acc[m]))));
        }
    }
#pragma unroll
    for (int m = 0; m < 16; ++m)
        out[(size_t)(m0 + m) * 128 + c] = 1.f / (1.f + __expf(-acc[m]));
}

// ---------------------------------------------------------------------------
extern "C" void kernel_launch(void* const* d_in, const int* in_sizes, int n_in,
                              void* d_out, int out_size, void* d_ws, size_t ws_size,
                              hipStream_t stream)
{
    const float* src      = (const float*)d_in[0];
    const float* trg      = (const float*)d_in[1];
    const float* eWih0    = (const float*)d_in[2];
    const float* eWhh0    = (const float*)d_in[3];
    const float* ebih0    = (const float*)d_in[4];
    const float* ebhh0    = (const float*)d_in[5];
    const float* eWih1    = (const float*)d_in[6];
    const float* eWhh1    = (const float*)d_in[7];
    const float* ebih1    = (const float*)d_in[8];
    const float* ebhh1    = (const float*)d_in[9];
    const float* dWih0    = (const float*)d_in[10];
    const float* dWhh0    = (const float*)d_in[11];
    const float* dbih0    = (const float*)d_in[12];
    const float* dbhh0    = (const float*)d_in[13];
    const float* dWih1    = (const float*)d_in[14];
    const float* dWhh1    = (const float*)d_in[15];
    const float* dbih1    = (const float*)d_in[16];
    const float* dbhh1    = (const float*)d_in[17];
    const float* Wout     = (const float*)d_in[18];
    const float* bout     = (const float*)d_in[19];

    char* ws = (char*)d_ws;
    float*              gx   = (float*)(ws + OFF_GX);
    float*              ys   = (float*)(ws + OFF_YS);
    unsigned long long* recE = (unsigned long long*)(ws + OFF_RECE);
    unsigned long long* recD = (unsigned long long*)(ws + OFF_RECD);
    float*              WT   = (float*)(ws + OFF_WT);

    hipFuncSetAttribute(reinterpret_cast<const void*>(seq2),
                        hipFuncAttributeMaxDynamicSharedMemorySize, LDS_BYTES);

    hipLaunchKernelGGL(transposeW, dim3(256), dim3(256), 0, stream, Wout, WT, recE);

    // ---- encoder ----
    hipLaunchKernelGGL(gemm_gx, dim3(LL / 16, 6), dim3(256), 0, stream,
                       src, eWih0, ebih0, gx, 0);
    hipLaunchKernelGGL(seq2, dim3(NB), dim3(256), LDS_BYTES, stream,
                       gx, eWhh0, eWih1, eWhh1, ebhh0, ebih1, ebhh1,
                       recE, (float*)nullptr);

    // ---- handoff + decoder ----
    hipLaunchKernelGGL(handoff, dim3(4), dim3(256), 0, stream, recE, recD);
    hipLaunchKernelGGL(gemm_gx, dim3(LL / 16, 6), dim3(256), 0, stream,
                       trg, dWih0, dbih0, gx, 1);
    hipLaunchKernelGGL(seq2, dim3(NB), dim3(256), LDS_BYTES, stream,
                       gx, dWhh0, dWih1, dWhh1, dbhh0, dbih1, dbhh1,
                       recD, ys);

    // ---- output projection ----
    hipLaunchKernelGGL(out_proj, dim3(LL / 16), dim3(128), 0, stream,
                       ys, WT, bout, (float*)d_out);

    (void)in_sizes; (void)n_in; (void)out_size; (void)ws_size;
}

// Round 3
// 37321.420 us; speedup vs baseline: 2.4943x; 1.4255x over previous
//
#include <hip/hip_runtime.h>

// Problem constants
#define Hh   512
#define Vv   128
#define LL   8192
#define G3   1536      // 3*H
#define NBK  256       // seq2 blocks: one wave each, owns 2 h0 + 2 h1 elements
#define NPAIR 1024     // pairs per record slot: h0[512] ++ h1[512]

// workspace layout (bytes)
#define OFF_GX   0ull                       // 8192*1536*4 = 50,331,648
#define OFF_YS   50331648ull                // 8192*512*4  = 16,777,216
#define OFF_RECE 67108864ull                // 2*1024*8    = 16,384
#define OFF_RECD (OFF_RECE + 16384ull)      // 16,384
#define OFF_WT   (OFF_RECD + 16384ull)      // 512*128*4   = 262,144

__device__ __forceinline__ float sigm(float x)  { return 1.f / (1.f + __expf(-x)); }
__device__ __forceinline__ float tanha(float x) { return 2.f / (1.f + __expf(-2.f * x)) - 1.f; }

__device__ __forceinline__ unsigned long long packpair(float v, int t) {
    return ((unsigned long long)(unsigned)t << 32) | (unsigned long long)__float_as_uint(v);
}
__device__ __forceinline__ int   pair_tag(unsigned long long p) { return (int)(p >> 32); }
__device__ __forceinline__ float pair_val(unsigned long long p) { return __uint_as_float((unsigned)p); }

// ---------------------------------------------------------------------------
// gx = X @ Wih^T + bih  (layer-0 input pre-activations, fully parallel)
// ---------------------------------------------------------------------------
__global__ __launch_bounds__(256) void gemm_gx(
    const float* __restrict__ X, const float* __restrict__ Wih,
    const float* __restrict__ bih, float* __restrict__ gxo, int shift_relu)
{
    __shared__ float xs[16][128];
    const int tid = threadIdx.x;
    const int m0  = blockIdx.x * 16;
    const int c   = blockIdx.y * 256 + tid;   // 0..1535 (row of Wih)

    for (int i = tid; i < 16 * 128; i += 256) {
        const int r = i >> 7, k = i & 127;
        int srow = m0 + r;
        if (shift_relu) srow = (srow == 0) ? 0 : (srow - 1);
        float v = X[(size_t)srow * Vv + k];
        if (shift_relu) v = fmaxf(v, 0.f);
        xs[r][k] = v;
    }
    __syncthreads();

    const float4* wp = (const float4*)(Wih + (size_t)c * Vv);
    float4 wr[32];
#pragma unroll
    for (int q = 0; q < 32; ++q) wr[q] = wp[q];
    const float bb = bih[c];

    for (int m = 0; m < 16; ++m) {
        const float4* xp = (const float4*)xs[m];
        float acc = bb;
#pragma unroll
        for (int q = 0; q < 32; ++q) {
            const float4 x4 = xp[q];
            acc = fmaf(wr[q].x, x4.x, acc); acc = fmaf(wr[q].y, x4.y, acc);
            acc = fmaf(wr[q].z, x4.z, acc); acc = fmaf(wr[q].w, x4.w, acc);
        }
        gxo[(size_t)(m0 + m) * G3 + c] = acc;
    }
}

// ---------------------------------------------------------------------------
// Persistent 2-layer GRU scan: 256 blocks x 1 wave. No LDS, no __syncthreads.
// Block b owns h0 elements {2b,2b+1} and h1 elements {2b,2b+1}: 18 dot-rows,
// weights live in VGPRs (rotated K-layout so element 2b sits in lane0/reg0).
// Record tau = { h0(tau), h1(tau-1) } as (value,tag) pairs, 2-slot ring.
// Per-lane poll + __all; pair-merged 64-lane butterfly reduction; gates on
// lanes 0-3; 4 fire-and-forget pair publishes.
// ---------------------------------------------------------------------------
__global__ __launch_bounds__(64, 1) void seq2(
    const float* __restrict__ gx,
    const float* __restrict__ Whh0, const float* __restrict__ Wih1,
    const float* __restrict__ Whh1,
    const float* __restrict__ bhh0, const float* __restrict__ bih1,
    const float* __restrict__ bhh1,
    unsigned long long* __restrict__ rec,
    float* __restrict__ ys)
{
    const int bid  = blockIdx.x, lane = threadIdx.x;
    const int e0   = 2 * bid;

    // rotated per-lane K offsets: element e0+i lands in lane i, reg 0
    int off[8];
#pragma unroll
    for (int j = 0; j < 8; ++j) off[j] = (e0 + lane + 64 * j) & 511;

    // one-time: stage 18 weight rows into registers (row r = m*6 + g*2 + i)
    float w[18][8];
#pragma unroll
    for (int m = 0; m < 3; ++m) {
        const float* mat = (m == 0) ? Whh0 : (m == 1) ? Wih1 : Whh1;
#pragma unroll
        for (int g = 0; g < 3; ++g)
#pragma unroll
            for (int i = 0; i < 2; ++i) {
                const float* row = mat + (size_t)(g * Hh + e0 + i) * Hh;
#pragma unroll
                for (int j = 0; j < 8; ++j) w[m * 6 + g * 2 + i][j] = row[off[j]];
            }
    }

    // biases: lanes 0,1 = layer0 elem e0+lane; lanes 2,3 = layer1 elem e0+(lane&1)
    float b_r = 0.f, b_z = 0.f, b_n1 = 0.f, b_n2 = 0.f;
    if (lane < 2) {
        const int e = e0 + lane;
        b_r = bhh0[e]; b_z = bhh0[Hh + e]; b_n1 = bhh0[2 * Hh + e];
    } else if (lane < 4) {
        const int e = e0 + (lane & 1);
        b_r  = bih1[e] + bhh1[e];
        b_z  = bih1[Hh + e] + bhh1[Hh + e];
        b_n1 = bih1[2 * Hh + e];      // x-side n bias
        b_n2 = bhh1[2 * Hh + e];      // h-side n bias (inside r*(.))
    }

    for (int tau = 0; tau <= LL; ++tau) {
        // prefetch gx row early (latency hides under the poll)
        float xr = 0.f, xz = 0.f, xn = 0.f;
        if (lane < 2 && tau < LL) {
            const size_t gb = (size_t)tau * G3 + e0 + lane;
            xr = gx[gb]; xz = gx[gb + Hh]; xn = gx[gb + 2 * Hh];
        }

        // per-lane poll of record tau-1 (no block barrier; wave __all only)
        const int need = tau - 1;
        const unsigned long long* rp = rec + (size_t)((tau - 1) & 1) * NPAIR;
        unsigned long long p0[8], p1[8];
        int ok;
        do {
#pragma unroll
            for (int j = 0; j < 8; ++j)
                p0[j] = __hip_atomic_load(rp + off[j],      __ATOMIC_RELAXED, __HIP_MEMORY_SCOPE_AGENT);
#pragma unroll
            for (int j = 0; j < 8; ++j)
                p1[j] = __hip_atomic_load(rp + Hh + off[j], __ATOMIC_RELAXED, __HIP_MEMORY_SCOPE_AGENT);
            ok = 1;
#pragma unroll
            for (int j = 0; j < 8; ++j)
                ok &= (pair_tag(p0[j]) >= need) & (pair_tag(p1[j]) >= need);
        } while (!__all(ok));

        float h0v[8], h1v[8];
#pragma unroll
        for (int j = 0; j < 8; ++j) { h0v[j] = pair_val(p0[j]); h1v[j] = pair_val(p1[j]); }

        // 18 register dots: rows 0..11 @ h0(tau-1), rows 12..17 @ h1(tau-2)
        float acc[18];
#pragma unroll
        for (int r = 0; r < 18; ++r) acc[r] = 0.f;
#pragma unroll
        for (int j = 0; j < 8; ++j) {
#pragma unroll
            for (int r = 0; r < 12; ++r) acc[r] = fmaf(w[r][j], h0v[j], acc[r]);
#pragma unroll
            for (int r = 12; r < 18; ++r) acc[r] = fmaf(w[r][j], h1v[j], acc[r]);
        }

        // pair-merged butterfly: sred[k] = row 2k sum (even lanes) / 2k+1 (odd)
        float sred[9];
#pragma unroll
        for (int k = 0; k < 9; ++k) {
            float a = acc[2 * k], c = acc[2 * k + 1];
            a += __shfl_xor(a, 1);
            c += __shfl_xor(c, 1);
            float m = (lane & 1) ? c : a;
            m += __shfl_xor(m, 2);  m += __shfl_xor(m, 4);
            m += __shfl_xor(m, 8);  m += __shfl_xor(m, 16);
            m += __shfl_xor(m, 32);
            sred[k] = m;
        }

        // h1prev[e0+(lane&1)] for lanes 2,3 (source lanes 0,1 hold it in reg0)
        const float h1p = __shfl(h1v[0], lane & 1);

        unsigned long long* recw = rec + (size_t)(tau & 1) * NPAIR;
        if (lane < 2) {
            if (tau < LL) {   // layer 0, element e0+lane; h0prev local in h0v[0]
                const float rg = sigm(xr + sred[0] + b_r);
                const float zg = sigm(xz + sred[1] + b_z);
                const float ng = tanha(xn + rg * (sred[2] + b_n1));
                const float hnew = (1.f - zg) * ng + zg * h0v[0];
                __hip_atomic_store(recw + e0 + lane, packpair(hnew, tau),
                                   __ATOMIC_RELAXED, __HIP_MEMORY_SCOPE_AGENT);
            }
        } else if (lane < 4) { // layer 1, element e0+(lane&1), step tau-1
            const int e = e0 + (lane & 1);
            float hnew;
            if (tau >= 1) {
                const float rg = sigm(sred[3] + sred[6] + b_r);
                const float zg = sigm(sred[4] + sred[7] + b_z);
                const float ng = tanha(sred[5] + b_n1 + rg * (sred[8] + b_n2));
                hnew = (1.f - zg) * ng + zg * h1p;
                if (ys) ys[(size_t)(tau - 1) * Hh + e] = hnew;
            } else {
                hnew = h1p;   // pass initial h1 through as "h1(-1)"
            }
            __hip_atomic_store(recw + Hh + e, packpair(hnew, tau),
                               __ATOMIC_RELAXED, __HIP_MEMORY_SCOPE_AGENT);
        }
    }
}

// ---------------------------------------------------------------------------
// WoutT + encoder record init (slot1: h=0 tag=-1; slot0: tag=-2)
// ---------------------------------------------------------------------------
__global__ __launch_bounds__(256) void transposeW(const float* __restrict__ W,
                                                  float* __restrict__ WT,
                                                  unsigned long long* __restrict__ encr)
{
    const int i = blockIdx.x * 256 + threadIdx.x;  // 0..65535
    WT[(i & 511) * 128 + (i >> 9)] = W[i];
    if (i < NPAIR) {
        __hip_atomic_store(encr + NPAIR + i, packpair(0.f, -1),
                           __ATOMIC_RELAXED, __HIP_MEMORY_SCOPE_AGENT);
        __hip_atomic_store(encr + i, packpair(0.f, -2),
                           __ATOMIC_RELAXED, __HIP_MEMORY_SCOPE_AGENT);
    }
}

// ---------------------------------------------------------------------------
// encoder -> decoder handoff. enc h0(L-1): slot1 pairs [0..511] (tick L-1);
// enc h1(L-1): slot0 pairs [512..1023] (tick L). dec slot1 tag=-1, slot0 tag=-2.
// ---------------------------------------------------------------------------
__global__ __launch_bounds__(256) void handoff(const unsigned long long* __restrict__ encr,
                                               unsigned long long* __restrict__ decr)
{
    const int p = blockIdx.x * 256 + threadIdx.x;  // 0..1023
    const unsigned long long src = __hip_atomic_load(
        encr + (p < Hh ? NPAIR : 0) + p, __ATOMIC_RELAXED, __HIP_MEMORY_SCOPE_AGENT);
    __hip_atomic_store(decr + NPAIR + p, packpair(pair_val(src), -1),
                       __ATOMIC_RELAXED, __HIP_MEMORY_SCOPE_AGENT);
    __hip_atomic_store(decr + p, packpair(0.f, -2),
                       __ATOMIC_RELAXED, __HIP_MEMORY_SCOPE_AGENT);
}

// ---------------------------------------------------------------------------
// out = sigmoid(ys @ Wout^T + bout)
// ---------------------------------------------------------------------------
__global__ __launch_bounds__(128) void out_proj(
    const float* __restrict__ ys, const float* __restrict__ WT,
    const float* __restrict__ bout, float* __restrict__ out)
{
    __shared__ float yss[16][512];
    const int tid = threadIdx.x;
    const int m0  = blockIdx.x * 16;

    for (int i = tid; i < 16 * 512; i += 128)
        yss[i >> 9][i & 511] = ys[(size_t)(m0 + (i >> 9)) * 512 + (i & 511)];
    __syncthreads();

    const int c = tid;  // 0..127
    float acc[16];
    const float b = bout[c];
#pragma unroll
    for (int m = 0; m < 16; ++m) acc[m] = b;

    for (int k4 = 0; k4 < 128; ++k4) {
        const float w0 = WT[(4 * k4 + 0) * 128 + c];
        const float w1 = WT[(4 * k4 + 1) * 128 + c];
        const float w2 = WT[(4 * k4 + 2) * 128 + c];
        const float w3 = WT[(4 * k4 + 3) * 128 + c];
#pragma unroll
        for (int m = 0; m < 16; ++m) {
            const float4 yv = *(const float4*)&yss[m][4 * k4];
            acc[m] = fmaf(w0, yv.x, fmaf(w1, yv.y, fmaf(w2, yv.z, fmaf(w3, yv.w, acc[m]))));
        }
    }
#pragma unroll
    for (int m = 0; m < 16; ++m)
        out[(size_t)(m0 + m) * 128 + c] = 1.f / (1.f + __expf(-acc[m]));
}

// ---------------------------------------------------------------------------
extern "C" void kernel_launch(void* const* d_in, const int* in_sizes, int n_in,
                              void* d_out, int out_size, void* d_ws, size_t ws_size,
                              hipStream_t stream)
{
    const float* src      = (const float*)d_in[0];
    const float* trg      = (const float*)d_in[1];
    const float* eWih0    = (const float*)d_in[2];
    const float* eWhh0    = (const float*)d_in[3];
    const float* ebih0    = (const float*)d_in[4];
    const float* ebhh0    = (const float*)d_in[5];
    const float* eWih1    = (const float*)d_in[6];
    const float* eWhh1    = (const float*)d_in[7];
    const float* ebih1    = (const float*)d_in[8];
    const float* ebhh1    = (const float*)d_in[9];
    const float* dWih0    = (const float*)d_in[10];
    const float* dWhh0    = (const float*)d_in[11];
    const float* dbih0    = (const float*)d_in[12];
    const float* dbhh0    = (const float*)d_in[13];
    const float* dWih1    = (const float*)d_in[14];
    const float* dWhh1    = (const float*)d_in[15];
    const float* dbih1    = (const float*)d_in[16];
    const float* dbhh1    = (const float*)d_in[17];
    const float* Wout     = (const float*)d_in[18];
    const float* bout     = (const float*)d_in[19];

    char* ws = (char*)d_ws;
    float*              gx   = (float*)(ws + OFF_GX);
    float*              ys   = (float*)(ws + OFF_YS);
    unsigned long long* recE = (unsigned long long*)(ws + OFF_RECE);
    unsigned long long* recD = (unsigned long long*)(ws + OFF_RECD);
    float*              WT   = (float*)(ws + OFF_WT);

    hipLaunchKernelGGL(transposeW, dim3(256), dim3(256), 0, stream, Wout, WT, recE);

    // ---- encoder ----
    hipLaunchKernelGGL(gemm_gx, dim3(LL / 16, 6), dim3(256), 0, stream,
                       src, eWih0, ebih0, gx, 0);
    hipLaunchKernelGGL(seq2, dim3(NBK), dim3(64), 0, stream,
                       gx, eWhh0, eWih1, eWhh1, ebhh0, ebih1, ebhh1,
                       recE, (float*)nullptr);

    // ---- handoff + decoder ----
    hipLaunchKernelGGL(handoff, dim3(4), dim3(256), 0, stream, recE, recD);
    hipLaunchKernelGGL(gemm_gx, dim3(LL / 16, 6), dim3(256), 0, stream,
                       trg, dWih0, dbih0, gx, 1);
    hipLaunchKernelGGL(seq2, dim3(NBK), dim3(64), 0, stream,
                       gx, dWhh0, dWih1, dWhh1, dbhh0, dbih1, dbhh1,
                       recD, ys);

    // ---- output projection ----
    hipLaunchKernelGGL(out_proj, dim3(LL / 16), dim3(128), 0, stream,
                       ys, WT, bout, (float*)d_out);

    (void)in_sizes; (void)n_in; (void)out_size; (void)ws_size;
}